// Round 4
// baseline (333.267 us; speedup 1.0000x reference)
//
#include <hip/hip_runtime.h>
#include <math.h>

#define NN 50000
#define NPAD 50048      // 782 * 64
#define NE 600000
#define H 128
#define ET 8
#define EPS 1e-5f
#define INVSQ 0.08838834764831845f  // 1/sqrt(128)

typedef __attribute__((ext_vector_type(8))) short bf16x8;
typedef __attribute__((ext_vector_type(8))) unsigned short u16x8;
typedef __attribute__((ext_vector_type(4))) float f32x4;

static __device__ inline float bf_lo(unsigned int w) { return __uint_as_float(w << 16); }
static __device__ inline float bf_hi(unsigned int w) { return __uint_as_float(w & 0xFFFF0000u); }
static __device__ inline float bfu(unsigned short v) {
  return __uint_as_float((unsigned int)v << 16);
}
static __device__ inline unsigned short f2bf(float f) {
  unsigned int u = __float_as_uint(f);
  return (unsigned short)((u + 0x7FFFu + ((u >> 16) & 1u)) >> 16);  // RNE
}

// ================= fused prep: hidden->bf16, weights->bf16^T, etype tables, degree hist =======
#define PH_B 3125
#define PW_B 384
#define ET_B 8
#define HIST_B 2344

__global__ __launch_bounds__(256) void prep_all_kernel(
    const float* __restrict__ hidden, const float* __restrict__ edge_emb,
    const float* __restrict__ Wq, const float* __restrict__ Wk, const float* __restrict__ Wv,
    const float* __restrict__ W1, const float* __restrict__ W2,
    const float* __restrict__ Web, const float* __restrict__ beb,
    const int* __restrict__ tgt,
    unsigned short* __restrict__ hcat, unsigned short* __restrict__ WqkvT,
    unsigned short* __restrict__ W1T, unsigned short* __restrict__ W2T,
    float* __restrict__ Kef, float* __restrict__ Vef, float* __restrict__ ebuf,
    int* __restrict__ deg) {
  const int blk = blockIdx.x;
  const int t = threadIdx.x;
  if (blk < PH_B) {
    // hidden fp32 -> bf16 into hcat[:, 0:128] (row stride 256)
    int g = blk * 256 + t;  // NN*16 = 800000 exactly
    int row = g >> 4, seg = g & 15;
    const float4* src = (const float4*)(hidden + (size_t)row * 128 + seg * 8);
    float4 x0 = src[0], x1 = src[1];
    u16x8 o;
    o[0] = f2bf(x0.x); o[1] = f2bf(x0.y); o[2] = f2bf(x0.z); o[3] = f2bf(x0.w);
    o[4] = f2bf(x1.x); o[5] = f2bf(x1.y); o[6] = f2bf(x1.z); o[7] = f2bf(x1.w);
    *(u16x8*)(hcat + (size_t)row * 256 + seg * 8) = o;
  } else if (blk < PH_B + PW_B) {
    int idx = (blk - PH_B) * 256 + t;
    if (idx < 49152) {
      int r = idx >> 7, k = idx & 127;
      const float* W = (r < 128) ? Wq : (r < 256) ? Wk : Wv;
      WqkvT[idx] = f2bf(W[k * 128 + (r & 127)]);
    } else if (idx < 81920) {
      int j = idx - 49152;
      int r = j >> 8, k = j & 255;
      W1T[j] = f2bf(W1[k * 128 + r]);
    } else if (idx < 98304) {
      int j = idx - 81920;
      int r = j >> 7, k = j & 127;
      W2T[j] = f2bf(W2[k * 128 + r]);
    }
  } else if (blk < PH_B + PW_B + ET_B) {
    // per-edge-type tables (fp32): Kef = ee@Wk, Vef = ee@Wv, eb = ee@Web + beb
    int e = blk - (PH_B + PW_B);
    if (t < 128) {
      float sk = 0.f, sv = 0.f;
      for (int i = 0; i < 128; ++i) {
        float ev = edge_emb[e * 128 + i];
        sk = fmaf(ev, Wk[i * 128 + t], sk);
        sv = fmaf(ev, Wv[i * 128 + t], sv);
      }
      Kef[e * 128 + t] = sk;
      Vef[e * 128 + t] = sv;
    } else if (t == 128) {
      float s2 = beb[0];
      for (int i = 0; i < 128; ++i) s2 = fmaf(edge_emb[e * 128 + i], Web[i], s2);
      ebuf[e] = s2;
    }
  } else {
    int e = (blk - (PH_B + PW_B + ET_B)) * 256 + t;
    if (e < NE) atomicAdd(&deg[tgt[e]], 1);
  }
}

// ---------------- QKV GEMM via MFMA -> Qb (pre-scaled bf16), KV interleaved ----------------
__global__ __launch_bounds__(256) void qkv_mfma_kernel(
    const unsigned short* __restrict__ hcat, const unsigned short* __restrict__ WqkvT,
    const float* __restrict__ bq, const float* __restrict__ bk, const float* __restrict__ bv,
    unsigned short* __restrict__ Qb, unsigned short* __restrict__ KV_u16) {
  __shared__ unsigned short stage[64][392];
  const int tid = threadIdx.x;
  const int w = tid >> 6, l = tid & 63;
  const int lr = l & 15, lg = l >> 4;
  const int blk = blockIdx.x;

  f32x4 acc[4][6] = {};
  const unsigned short* Ab = hcat + (size_t)(blk * 64 + lr) * 256 + lg * 8;
  const unsigned short* Bb = WqkvT + (size_t)(w * 96 + lr) * 128 + lg * 8;
#pragma unroll
  for (int ks = 0; ks < 4; ++ks) {
    bf16x8 a[4];
#pragma unroll
    for (int mt = 0; mt < 4; ++mt) a[mt] = *(const bf16x8*)(Ab + mt * 16 * 256 + ks * 32);
#pragma unroll
    for (int ct = 0; ct < 6; ++ct) {
      bf16x8 b = *(const bf16x8*)(Bb + ct * 16 * 128 + ks * 32);
#pragma unroll
      for (int mt = 0; mt < 4; ++mt)
        acc[mt][ct] = __builtin_amdgcn_mfma_f32_16x16x32_bf16(a[mt], b, acc[mt][ct], 0, 0, 0);
    }
  }
  // bias + scale + convert -> LDS stage in FINAL memory layout:
  //   row u16 layout: [0,128)   = Q col c (scaled by 1/sqrt(128))
  //                   [128,384) = KV interleave: K col j -> 128 + (j>>1)*4 + (j&1)
  //                               V col j -> 128 + (j>>1)*4 + 2 + (j&1)
#pragma unroll
  for (int ct = 0; ct < 6; ++ct) {
    int c = w * 96 + ct * 16 + lr;
    float bias = (c < 128) ? bq[c] : (c < 256) ? bk[c - 128] : bv[c - 256];
    float sc = (c < 128) ? INVSQ : 1.f;
    int off;
    if (c < 128) off = c;
    else if (c < 256) { int j = c - 128; off = 128 + ((j >> 1) << 2) + (j & 1); }
    else { int j = c - 256; off = 128 + ((j >> 1) << 2) + 2 + (j & 1); }
#pragma unroll
    for (int mt = 0; mt < 4; ++mt)
#pragma unroll
      for (int j = 0; j < 4; ++j)
        stage[mt * 16 + lg * 4 + j][off] = f2bf((acc[mt][ct][j] + bias) * sc);
  }
  __syncthreads();
  // coalesced 16B stores
  for (int idx = tid; idx < 64 * 48; idx += 256) {
    int r = idx / 48, g = idx % 48;
    int row = blk * 64 + r;
    if (row >= NN) continue;
    u16x8 v = *(const u16x8*)(&stage[r][g * 8]);
    if (g < 16) *(u16x8*)(Qb + (size_t)row * 128 + g * 8) = v;
    else *(u16x8*)(KV_u16 + (size_t)row * 256 + (g - 16) * 8) = v;
  }
}

// ---------------- qke table: qke[n][et] = Qb[n,:]·Kef[et,:] + eb[et] ----------------
__global__ __launch_bounds__(256) void qke_kernel(const unsigned short* __restrict__ Qb,
                                                  const float* __restrict__ Kef,
                                                  const float* __restrict__ ebuf,
                                                  float* __restrict__ qke) {
  const int wid = (blockIdx.x * 256 + threadIdx.x) >> 6;  // 4 nodes/block, exact 50000
  const int lane = threadIdx.x & 63;
  const int et = lane >> 3, part = lane & 7;
  const unsigned short* q = Qb + (size_t)wid * 128 + part * 16;
  u16x8 q0 = *(const u16x8*)q;
  u16x8 q1 = *(const u16x8*)(q + 8);
  const float4* kf = (const float4*)(Kef + et * 128 + part * 16);
  float4 k0 = kf[0], k1 = kf[1], k2 = kf[2], k3 = kf[3];
  float d = 0.f;
  d = fmaf(bfu(q0[0]), k0.x, d); d = fmaf(bfu(q0[1]), k0.y, d);
  d = fmaf(bfu(q0[2]), k0.z, d); d = fmaf(bfu(q0[3]), k0.w, d);
  d = fmaf(bfu(q0[4]), k1.x, d); d = fmaf(bfu(q0[5]), k1.y, d);
  d = fmaf(bfu(q0[6]), k1.z, d); d = fmaf(bfu(q0[7]), k1.w, d);
  d = fmaf(bfu(q1[0]), k2.x, d); d = fmaf(bfu(q1[1]), k2.y, d);
  d = fmaf(bfu(q1[2]), k2.z, d); d = fmaf(bfu(q1[3]), k2.w, d);
  d = fmaf(bfu(q1[4]), k3.x, d); d = fmaf(bfu(q1[5]), k3.y, d);
  d = fmaf(bfu(q1[6]), k3.z, d); d = fmaf(bfu(q1[7]), k3.w, d);
#pragma unroll
  for (int o = 4; o >= 1; o >>= 1) d += __shfl_xor(d, o);
  if (part == 0) qke[(size_t)wid * 8 + et] = d + ebuf[et];
}

// ---------------- CSR build: scans + scatter ----------------
__global__ __launch_bounds__(256) void scan1_kernel(const int* __restrict__ deg,
                                                    int* __restrict__ excl,
                                                    int* __restrict__ sums) {
  __shared__ int buf[256];
  int idx = blockIdx.x * 256 + threadIdx.x;
  int v = (idx < NN) ? deg[idx] : 0;
  buf[threadIdx.x] = v;
  __syncthreads();
  for (int o = 1; o < 256; o <<= 1) {
    int tv = (threadIdx.x >= o) ? buf[threadIdx.x - o] : 0;
    __syncthreads();
    buf[threadIdx.x] += tv;
    __syncthreads();
  }
  if (idx < NN) excl[idx] = buf[threadIdx.x] - v;
  if (threadIdx.x == 255) sums[blockIdx.x] = buf[255];
}

__global__ __launch_bounds__(256) void scan2_kernel(int* __restrict__ sums, int nb) {
  __shared__ int buf[256];
  int v = (threadIdx.x < nb) ? sums[threadIdx.x] : 0;
  buf[threadIdx.x] = v;
  __syncthreads();
  for (int o = 1; o < 256; o <<= 1) {
    int tv = (threadIdx.x >= o) ? buf[threadIdx.x - o] : 0;
    __syncthreads();
    buf[threadIdx.x] += tv;
    __syncthreads();
  }
  if (threadIdx.x < nb) sums[threadIdx.x] = buf[threadIdx.x] - v;  // exclusive
}

__global__ __launch_bounds__(256) void scan3_kernel(const int* __restrict__ excl,
                                                    const int* __restrict__ sums,
                                                    int* __restrict__ row_off,
                                                    int* __restrict__ cursor) {
  int idx = blockIdx.x * 256 + threadIdx.x;
  if (idx < NN) {
    int r = excl[idx] + sums[blockIdx.x];
    row_off[idx] = r;
    cursor[idx] = r;
  }
  if (idx == 0) row_off[NN] = NE;
}

__global__ void scatter_kernel(const int* __restrict__ src, const int* __restrict__ tgt,
                               const int* __restrict__ et, int* __restrict__ cursor,
                               int* __restrict__ packed) {
  int e = blockIdx.x * blockDim.x + threadIdx.x;
  if (e < NE) {
    int pos = atomicAdd(&cursor[tgt[e]], 1);
    packed[pos] = src[e] | (et[e] << 16);  // src < 65536, et < 8
  }
}

// ---------------- attention: one wave/node, 16 lanes/edge, 4 edges/wave ----------------
// No-max softmax (logit range ~±8 is safe in fp32). qke folds q·Ke + eb per (node, etype).
__global__ __launch_bounds__(256) void attn_kernel(
    const unsigned short* __restrict__ Qb, const uint4* __restrict__ KV4,
    const float* __restrict__ qke, const float* __restrict__ Vef,
    const int* __restrict__ row_off, const int* __restrict__ packed,
    unsigned short* __restrict__ hcat_u16) {
  const int wid = (blockIdx.x * blockDim.x + threadIdx.x) >> 6;
  const int lane = threadIdx.x & 63;
  const int g = lane >> 4, m = lane & 15;
  const int beg = row_off[wid], end = row_off[wid + 1];
  // q: 8 cols starting 8m (bf16, pre-scaled by 1/sqrt(128))
  u16x8 qv = *(const u16x8*)(Qb + (size_t)wid * 128 + m * 8);
  float q[8];
#pragma unroll
  for (int j = 0; j < 8; ++j) q[j] = bfu(qv[j]);
  const float* qkb = qke + (size_t)wid * 8;
  float a[8] = {0.f, 0.f, 0.f, 0.f, 0.f, 0.f, 0.f, 0.f};
  float s = 0.f;
  for (int i = beg; i < end; i += 4) {
    int ii = i + g;
    bool valid = ii < end;
    int p = packed[valid ? ii : beg];
    int src = p & 0xFFFF, et = p >> 16;
    // KV row = 32 uint4; lane m reads uint4 2m, 2m+1 (cols 8m..8m+7)
    const uint4* row = KV4 + (size_t)src * 32 + m * 2;
    uint4 x0 = row[0], x1 = row[1];
    // x: {kpair, vpair, kpair, vpair}
    float d;
    d = bf_lo(x0.x) * q[0];
    d = fmaf(bf_hi(x0.x), q[1], d);
    d = fmaf(bf_lo(x0.z), q[2], d);
    d = fmaf(bf_hi(x0.z), q[3], d);
    d = fmaf(bf_lo(x1.x), q[4], d);
    d = fmaf(bf_hi(x1.x), q[5], d);
    d = fmaf(bf_lo(x1.z), q[6], d);
    d = fmaf(bf_hi(x1.z), q[7], d);
#pragma unroll
    for (int o = 8; o >= 1; o >>= 1) d += __shfl_xor(d, o);
    float pe = __expf(d + qkb[et]);
    pe = valid ? pe : 0.f;
    s += pe;
    const float4* vef = (const float4*)(Vef + et * 128 + m * 8);
    float4 v0 = vef[0], v1 = vef[1];
    a[0] = fmaf(pe, bf_lo(x0.y) + v0.x, a[0]);
    a[1] = fmaf(pe, bf_hi(x0.y) + v0.y, a[1]);
    a[2] = fmaf(pe, bf_lo(x0.w) + v0.z, a[2]);
    a[3] = fmaf(pe, bf_hi(x0.w) + v0.w, a[3]);
    a[4] = fmaf(pe, bf_lo(x1.y) + v1.x, a[4]);
    a[5] = fmaf(pe, bf_hi(x1.y) + v1.y, a[5]);
    a[6] = fmaf(pe, bf_lo(x1.w) + v1.z, a[6]);
    a[7] = fmaf(pe, bf_hi(x1.w) + v1.w, a[7]);
  }
  // cross-group reduce (xor 16, 32)
#pragma unroll
  for (int o = 16; o <= 32; o <<= 1) {
    s += __shfl_xor(s, o);
#pragma unroll
    for (int j = 0; j < 8; ++j) a[j] += __shfl_xor(a[j], o);
  }
  if (g == 0) {
    float inv = (s > 0.f) ? 1.f / s : 0.f;
    u16x8 o;
#pragma unroll
    for (int j = 0; j < 8; ++j) o[j] = f2bf(a[j] * inv);
    *(u16x8*)(hcat_u16 + (size_t)wid * 256 + 128 + m * 8) = o;
  }
}

// ---------------- FFN + residual + LayerNorm (MFMA) ----------------
__global__ __launch_bounds__(256) void ffn_mfma_kernel(
    const unsigned short* __restrict__ hcat, const float* __restrict__ hidden,
    const unsigned short* __restrict__ W1T, const unsigned short* __restrict__ W2T,
    const float* __restrict__ b1, const float* __restrict__ b2,
    const float* __restrict__ gamma, const float* __restrict__ beta,
    float* __restrict__ out) {
  __shared__ unsigned short mid[64][136];
  const int tid = threadIdx.x;
  const int w = tid >> 6, l = tid & 63;
  const int lr = l & 15, lg = l >> 4;
  const int m0 = blockIdx.x * 64 + w * 16;

  // GEMM1: [h|agg] (K=256) @ W1 -> 128, + b1, silu
  f32x4 acc[8] = {};
  const unsigned short* Ab = hcat + (size_t)(m0 + lr) * 256 + lg * 8;
  const unsigned short* Bb = W1T + (size_t)lr * 256 + lg * 8;
#pragma unroll
  for (int ks = 0; ks < 8; ++ks) {
    bf16x8 a = *(const bf16x8*)(Ab + ks * 32);
#pragma unroll
    for (int ct = 0; ct < 8; ++ct) {
      bf16x8 b = *(const bf16x8*)(Bb + ct * 16 * 256 + ks * 32);
      acc[ct] = __builtin_amdgcn_mfma_f32_16x16x32_bf16(a, b, acc[ct], 0, 0, 0);
    }
  }
#pragma unroll
  for (int ct = 0; ct < 8; ++ct) {
    int c = ct * 16 + lr;
    float bb = b1[c];
#pragma unroll
    for (int j = 0; j < 4; ++j) {
      float x = acc[ct][j] + bb;
      float sl = x / (1.f + __expf(-x));
      mid[w * 16 + lg * 4 + j][c] = f2bf(sl);
    }
  }
  __syncthreads();

  // GEMM2: mid (K=128) @ W2 -> 128
  f32x4 acc2[8] = {};
  const unsigned short* A2 = &mid[w * 16 + lr][0] + lg * 8;
  const unsigned short* B2 = W2T + (size_t)lr * 128 + lg * 8;
#pragma unroll
  for (int ks = 0; ks < 4; ++ks) {
    bf16x8 a = *(const bf16x8*)(A2 + ks * 32);
#pragma unroll
    for (int ct = 0; ct < 8; ++ct) {
      bf16x8 b = *(const bf16x8*)(B2 + ct * 16 * 128 + ks * 32);
      acc2[ct] = __builtin_amdgcn_mfma_f32_16x16x32_bf16(a, b, acc2[ct], 0, 0, 0);
    }
  }

  // epilogue: + b2 + residual, LayerNorm, store
  float ga[8], be[8], x[8][4];
#pragma unroll
  for (int ct = 0; ct < 8; ++ct) {
    int c = ct * 16 + lr;
    ga[ct] = gamma[c];
    be[ct] = beta[c];
    float bb = b2[c];
#pragma unroll
    for (int j = 0; j < 4; ++j) {
      int r = m0 + lg * 4 + j;
      float h = (r < NN) ? hidden[(size_t)r * 128 + c] : 0.f;
      x[ct][j] = acc2[ct][j] + bb + h;
    }
  }
#pragma unroll
  for (int j = 0; j < 4; ++j) {
    float s = 0.f, ss = 0.f;
#pragma unroll
    for (int ct = 0; ct < 8; ++ct) {
      s += x[ct][j];
      ss += x[ct][j] * x[ct][j];
    }
#pragma unroll
    for (int o = 8; o >= 1; o >>= 1) {
      s += __shfl_xor(s, o);
      ss += __shfl_xor(ss, o);
    }
    float mu = s * (1.f / 128.f);
    float inv = rsqrtf(ss * (1.f / 128.f) - mu * mu + EPS);
    int r = m0 + lg * 4 + j;
    if (r < NN) {
#pragma unroll
      for (int ct = 0; ct < 8; ++ct) {
        int c = ct * 16 + lr;
        out[(size_t)r * 128 + c] = (x[ct][j] - mu) * inv * ga[ct] + be[ct];
      }
    }
  }
}

extern "C" void kernel_launch(void* const* d_in, const int* in_sizes, int n_in,
                              void* d_out, int out_size, void* d_ws, size_t ws_size,
                              hipStream_t stream) {
  const float* hidden = (const float*)d_in[0];
  const int* edge_index = (const int*)d_in[1];
  const int* edge_type = (const int*)d_in[2];
  const float* edge_emb = (const float*)d_in[3];
  const float* Wq = (const float*)d_in[4];
  const float* bq = (const float*)d_in[5];
  const float* Wk = (const float*)d_in[6];
  const float* bk = (const float*)d_in[7];
  const float* Wv = (const float*)d_in[8];
  const float* bv = (const float*)d_in[9];
  const float* Web = (const float*)d_in[10];
  const float* beb = (const float*)d_in[11];
  const float* W1 = (const float*)d_in[12];
  const float* b1 = (const float*)d_in[13];
  const float* W2 = (const float*)d_in[14];
  const float* b2 = (const float*)d_in[15];
  const float* gamma = (const float*)d_in[16];
  const float* beta = (const float*)d_in[17];
  float* out = (float*)d_out;

  const int* srcp = edge_index;
  const int* tgtp = edge_index + NE;

  size_t off = 0;
  auto alloc = [&](size_t bytes) {
    void* p = (char*)d_ws + off;
    off += (bytes + 255) & ~(size_t)255;
    return p;
  };
  unsigned short* hcat = (unsigned short*)alloc((size_t)NPAD * 256 * 2);  // [h|agg] bf16
  unsigned short* Qb = (unsigned short*)alloc((size_t)NPAD * 128 * 2);    // pre-scaled
  unsigned short* KV = (unsigned short*)alloc((size_t)NPAD * 256 * 2);    // interleaved k/v pairs
  unsigned short* WqkvT = (unsigned short*)alloc(384 * 128 * 2);
  unsigned short* W1T = (unsigned short*)alloc(128 * 256 * 2);
  unsigned short* W2T = (unsigned short*)alloc(128 * 128 * 2);
  float* Kef = (float*)alloc(ET * H * 4);
  float* Vef = (float*)alloc(ET * H * 4);
  float* ebuf = (float*)alloc(ET * 4);
  float* qke = (float*)alloc((size_t)NN * 8 * 4);
  int* deg = (int*)alloc((size_t)NN * 4);
  int* excl = (int*)alloc((size_t)NN * 4);
  int* sums = (int*)alloc(256 * 4);
  int* row_off = (int*)alloc((size_t)(NN + 1) * 4);
  int* cursor = (int*)alloc((size_t)NN * 4);
  int* packed = (int*)alloc((size_t)NE * 4);

  hipMemsetAsync(deg, 0, (size_t)NN * 4, stream);

  const int scan_blocks = (NN + 255) / 256;  // 196

  prep_all_kernel<<<PH_B + PW_B + ET_B + HIST_B, 256, 0, stream>>>(
      hidden, edge_emb, Wq, Wk, Wv, W1, W2, Web, beb, tgtp, hcat, WqkvT, W1T, W2T, Kef, Vef,
      ebuf, deg);
  scan1_kernel<<<scan_blocks, 256, 0, stream>>>(deg, excl, sums);
  scan2_kernel<<<1, 256, 0, stream>>>(sums, scan_blocks);
  scan3_kernel<<<scan_blocks, 256, 0, stream>>>(excl, sums, row_off, cursor);
  scatter_kernel<<<(NE + 255) / 256, 256, 0, stream>>>(srcp, tgtp, edge_type, cursor, packed);
  qkv_mfma_kernel<<<NPAD / 64, 256, 0, stream>>>(hcat, WqkvT, bq, bk, bv, Qb, KV);
  qke_kernel<<<NN / 4, 256, 0, stream>>>(Qb, Kef, ebuf, qke);
  attn_kernel<<<(NN * 64) / 256, 256, 0, stream>>>(Qb, (const uint4*)KV, qke, Vef, row_off,
                                                   packed, hcat);
  ffn_mfma_kernel<<<NPAD / 64, 256, 0, stream>>>(hcat, hidden, W1T, W2T, b1, b2, gamma, beta,
                                                 out);
}

// Round 6
// 296.675 us; speedup vs baseline: 1.1233x; 1.1233x over previous
//
#include <hip/hip_runtime.h>
#include <math.h>

#define NN 50000
#define NPAD 50048      // 782 * 64
#define NTILES 3128     // NPAD / 16
#define NE 600000
#define H 128
#define ET 8
#define EPS 1e-5f
#define INVSQ 0.08838834764831845f  // 1/sqrt(128)

typedef __attribute__((ext_vector_type(8))) short bf16x8;
typedef __attribute__((ext_vector_type(8))) unsigned short u16x8;
typedef __attribute__((ext_vector_type(4))) float f32x4;

static __device__ inline float bf_lo(unsigned int w) { return __uint_as_float(w << 16); }
static __device__ inline float bf_hi(unsigned int w) { return __uint_as_float(w & 0xFFFF0000u); }
static __device__ inline float bfu(unsigned short v) {
  return __uint_as_float((unsigned int)v << 16);
}
static __device__ inline unsigned short f2bf(float f) {
  unsigned int u = __float_as_uint(f);
  return (unsigned short)((u + 0x7FFFu + ((u >> 16) & 1u)) >> 16);  // RNE
}

// ================= fused prep: hidden->bf16, weights->bf16^T, etype tables, degree hist =======
#define PH_B 3125
#define PW_B 384
#define ET_B 8
#define HIST_B 2344

__global__ __launch_bounds__(256) void prep_all_kernel(
    const float* __restrict__ hidden, const float* __restrict__ edge_emb,
    const float* __restrict__ Wq, const float* __restrict__ Wk, const float* __restrict__ Wv,
    const float* __restrict__ W1, const float* __restrict__ W2,
    const float* __restrict__ Web, const float* __restrict__ beb,
    const int* __restrict__ tgt,
    unsigned short* __restrict__ hcat, unsigned short* __restrict__ WqkvT,
    unsigned short* __restrict__ W1T, unsigned short* __restrict__ W2T,
    float* __restrict__ Kef, float* __restrict__ Vef, float* __restrict__ ebuf,
    int* __restrict__ deg) {
  const int blk = blockIdx.x;
  const int t = threadIdx.x;
  if (blk < PH_B) {
    // hidden fp32 -> bf16 into hcat[:, 0:128] (row stride 256)
    int g = blk * 256 + t;  // NN*16 = 800000 exactly
    int row = g >> 4, seg = g & 15;
    const float4* src = (const float4*)(hidden + (size_t)row * 128 + seg * 8);
    float4 x0 = src[0], x1 = src[1];
    u16x8 o;
    o[0] = f2bf(x0.x); o[1] = f2bf(x0.y); o[2] = f2bf(x0.z); o[3] = f2bf(x0.w);
    o[4] = f2bf(x1.x); o[5] = f2bf(x1.y); o[6] = f2bf(x1.z); o[7] = f2bf(x1.w);
    *(u16x8*)(hcat + (size_t)row * 256 + seg * 8) = o;
  } else if (blk < PH_B + PW_B) {
    int idx = (blk - PH_B) * 256 + t;
    if (idx < 49152) {
      int r = idx >> 7, k = idx & 127;
      const float* W = (r < 128) ? Wq : (r < 256) ? Wk : Wv;
      WqkvT[idx] = f2bf(W[k * 128 + (r & 127)]);
    } else if (idx < 81920) {
      int j = idx - 49152;
      int r = j >> 8, k = j & 255;
      W1T[j] = f2bf(W1[k * 128 + r]);
    } else if (idx < 98304) {
      int j = idx - 81920;
      int r = j >> 7, k = j & 127;
      W2T[j] = f2bf(W2[k * 128 + r]);
    }
  } else if (blk < PH_B + PW_B + ET_B) {
    // per-edge-type tables (fp32): Kef = ee@Wk, Vef = ee@Wv, eb = ee@Web + beb
    int e = blk - (PH_B + PW_B);
    if (t < 128) {
      float sk = 0.f, sv = 0.f;
      for (int i = 0; i < 128; ++i) {
        float ev = edge_emb[e * 128 + i];
        sk = fmaf(ev, Wk[i * 128 + t], sk);
        sv = fmaf(ev, Wv[i * 128 + t], sv);
      }
      Kef[e * 128 + t] = sk;
      Vef[e * 128 + t] = sv;
    } else if (t == 128) {
      float s2 = beb[0];
      for (int i = 0; i < 128; ++i) s2 = fmaf(edge_emb[e * 128 + i], Web[i], s2);
      ebuf[e] = s2;
    }
  } else {
    int e = (blk - (PH_B + PW_B + ET_B)) * 256 + t;
    if (e < NE) atomicAdd(&deg[tgt[e]], 1);
  }
}

// ---------------- QKV GEMM via MFMA -> Qb (pre-scaled bf16), KV interleaved ----------------
// 8 waves: 2 row-groups x 4 col-groups -> per-wave B panel is 1/4 size, occupancy 3 blocks/CU.
__global__ __launch_bounds__(512) void qkv_mfma_kernel(
    const unsigned short* __restrict__ hcat, const unsigned short* __restrict__ WqkvT,
    const float* __restrict__ bq, const float* __restrict__ bk, const float* __restrict__ bv,
    unsigned short* __restrict__ Qb, unsigned short* __restrict__ KV_u16) {
  __shared__ unsigned short stage[64][392];
  const int tid = threadIdx.x;
  const int w = tid >> 6, l = tid & 63;
  const int wr = w >> 2, wc = w & 3;
  const int lr = l & 15, lg = l >> 4;
  const int blk = blockIdx.x;

  f32x4 acc[2][6] = {};
  const unsigned short* Ab = hcat + (size_t)(blk * 64 + wr * 32 + lr) * 256 + lg * 8;
  const unsigned short* Bb = WqkvT + (size_t)(wc * 96 + lr) * 128 + lg * 8;
#pragma unroll
  for (int ks = 0; ks < 4; ++ks) {
    bf16x8 a0 = *(const bf16x8*)(Ab + ks * 32);
    bf16x8 a1 = *(const bf16x8*)(Ab + 16 * 256 + ks * 32);
#pragma unroll
    for (int ct = 0; ct < 6; ++ct) {
      bf16x8 b = *(const bf16x8*)(Bb + ct * 16 * 128 + ks * 32);
      acc[0][ct] = __builtin_amdgcn_mfma_f32_16x16x32_bf16(a0, b, acc[0][ct], 0, 0, 0);
      acc[1][ct] = __builtin_amdgcn_mfma_f32_16x16x32_bf16(a1, b, acc[1][ct], 0, 0, 0);
    }
  }
  // bias + scale + convert -> LDS stage in FINAL memory layout:
  //   row u16 layout: [0,128)   = Q col c (scaled by 1/sqrt(128))
  //                   [128,384) = KV interleave: K col j -> 128 + (j>>1)*4 + (j&1)
  //                               V col j -> 128 + (j>>1)*4 + 2 + (j&1)
#pragma unroll
  for (int ct = 0; ct < 6; ++ct) {
    int c = wc * 96 + ct * 16 + lr;
    float bias = (c < 128) ? bq[c] : (c < 256) ? bk[c - 128] : bv[c - 256];
    float sc = (c < 128) ? INVSQ : 1.f;
    int off;
    if (c < 128) off = c;
    else if (c < 256) { int j = c - 128; off = 128 + ((j >> 1) << 2) + (j & 1); }
    else { int j = c - 256; off = 128 + ((j >> 1) << 2) + 2 + (j & 1); }
#pragma unroll
    for (int mt = 0; mt < 2; ++mt)
#pragma unroll
      for (int j = 0; j < 4; ++j)
        stage[wr * 32 + mt * 16 + lg * 4 + j][off] = f2bf((acc[mt][ct][j] + bias) * sc);
  }
  __syncthreads();
  // coalesced 16B stores
  for (int idx = tid; idx < 64 * 48; idx += 512) {
    int r = idx / 48, g = idx % 48;
    int row = blk * 64 + r;
    if (row >= NN) continue;
    u16x8 v = *(const u16x8*)(&stage[r][g * 8]);
    if (g < 16) *(u16x8*)(Qb + (size_t)row * 128 + g * 8) = v;
    else *(u16x8*)(KV_u16 + (size_t)row * 256 + (g - 16) * 8) = v;
  }
}

// ---------------- qke table: qke[n][et] = Qb[n,:]·Kef[et,:] + eb[et] ----------------
__global__ __launch_bounds__(256) void qke_kernel(const unsigned short* __restrict__ Qb,
                                                  const float* __restrict__ Kef,
                                                  const float* __restrict__ ebuf,
                                                  float* __restrict__ qke) {
  const int wid = (blockIdx.x * 256 + threadIdx.x) >> 6;  // 4 nodes/block, exact 50000
  const int lane = threadIdx.x & 63;
  const int et = lane >> 3, part = lane & 7;
  const unsigned short* q = Qb + (size_t)wid * 128 + part * 16;
  u16x8 q0 = *(const u16x8*)q;
  u16x8 q1 = *(const u16x8*)(q + 8);
  const float4* kf = (const float4*)(Kef + et * 128 + part * 16);
  float4 k0 = kf[0], k1 = kf[1], k2 = kf[2], k3 = kf[3];
  float d = 0.f;
  d = fmaf(bfu(q0[0]), k0.x, d); d = fmaf(bfu(q0[1]), k0.y, d);
  d = fmaf(bfu(q0[2]), k0.z, d); d = fmaf(bfu(q0[3]), k0.w, d);
  d = fmaf(bfu(q0[4]), k1.x, d); d = fmaf(bfu(q0[5]), k1.y, d);
  d = fmaf(bfu(q0[6]), k1.z, d); d = fmaf(bfu(q0[7]), k1.w, d);
  d = fmaf(bfu(q1[0]), k2.x, d); d = fmaf(bfu(q1[1]), k2.y, d);
  d = fmaf(bfu(q1[2]), k2.z, d); d = fmaf(bfu(q1[3]), k2.w, d);
  d = fmaf(bfu(q1[4]), k3.x, d); d = fmaf(bfu(q1[5]), k3.y, d);
  d = fmaf(bfu(q1[6]), k3.z, d); d = fmaf(bfu(q1[7]), k3.w, d);
#pragma unroll
  for (int o = 4; o >= 1; o >>= 1) d += __shfl_xor(d, o);
  if (part == 0) qke[(size_t)wid * 8 + et] = d + ebuf[et];
}

// ---------------- CSR build: scans + scatter ----------------
__global__ __launch_bounds__(256) void scan1_kernel(const int* __restrict__ deg,
                                                    int* __restrict__ excl,
                                                    int* __restrict__ sums) {
  __shared__ int buf[256];
  int idx = blockIdx.x * 256 + threadIdx.x;
  int v = (idx < NN) ? deg[idx] : 0;
  buf[threadIdx.x] = v;
  __syncthreads();
  for (int o = 1; o < 256; o <<= 1) {
    int tv = (threadIdx.x >= o) ? buf[threadIdx.x - o] : 0;
    __syncthreads();
    buf[threadIdx.x] += tv;
    __syncthreads();
  }
  if (idx < NN) excl[idx] = buf[threadIdx.x] - v;
  if (threadIdx.x == 255) sums[blockIdx.x] = buf[255];
}

__global__ __launch_bounds__(256) void scan2_kernel(int* __restrict__ sums, int nb) {
  __shared__ int buf[256];
  int v = (threadIdx.x < nb) ? sums[threadIdx.x] : 0;
  buf[threadIdx.x] = v;
  __syncthreads();
  for (int o = 1; o < 256; o <<= 1) {
    int tv = (threadIdx.x >= o) ? buf[threadIdx.x - o] : 0;
    __syncthreads();
    buf[threadIdx.x] += tv;
    __syncthreads();
  }
  if (threadIdx.x < nb) sums[threadIdx.x] = buf[threadIdx.x] - v;  // exclusive
}

__global__ __launch_bounds__(256) void scan3_kernel(const int* __restrict__ excl,
                                                    const int* __restrict__ sums,
                                                    int* __restrict__ row_off,
                                                    int* __restrict__ cursor) {
  int idx = blockIdx.x * 256 + threadIdx.x;
  if (idx < NN) {
    int r = excl[idx] + sums[blockIdx.x];
    row_off[idx] = r;
    cursor[idx] = r;
  }
  if (idx == 0) row_off[NN] = NE;
}

__global__ void scatter_kernel(const int* __restrict__ src, const int* __restrict__ tgt,
                               const int* __restrict__ et, int* __restrict__ cursor,
                               int* __restrict__ packed) {
  int e = blockIdx.x * blockDim.x + threadIdx.x;
  if (e < NE) {
    int pos = atomicAdd(&cursor[tgt[e]], 1);
    packed[pos] = src[e] | (et[e] << 16);  // src < 65536, et < 8
  }
}

// ---------------- attention: one wave/node, 16 lanes/edge, 4 edges/wave ----------------
// No-max softmax (logit range ~±8 is safe in fp32). qke folds q·Ke + eb per (node, etype).
__global__ __launch_bounds__(256) void attn_kernel(
    const unsigned short* __restrict__ Qb, const uint4* __restrict__ KV4,
    const float* __restrict__ qke, const float* __restrict__ Vef,
    const int* __restrict__ row_off, const int* __restrict__ packed,
    unsigned short* __restrict__ hcat_u16) {
  const int wid = (blockIdx.x * blockDim.x + threadIdx.x) >> 6;
  const int lane = threadIdx.x & 63;
  const int g = lane >> 4, m = lane & 15;
  const int beg = row_off[wid], end = row_off[wid + 1];
  // q: 8 cols starting 8m (bf16, pre-scaled by 1/sqrt(128))
  u16x8 qv = *(const u16x8*)(Qb + (size_t)wid * 128 + m * 8);
  float q[8];
#pragma unroll
  for (int j = 0; j < 8; ++j) q[j] = bfu(qv[j]);
  const float* qkb = qke + (size_t)wid * 8;
  float a[8] = {0.f, 0.f, 0.f, 0.f, 0.f, 0.f, 0.f, 0.f};
  float s = 0.f;
  for (int i = beg; i < end; i += 4) {
    int ii = i + g;
    bool valid = ii < end;
    int p = packed[valid ? ii : beg];
    int src = p & 0xFFFF, et = p >> 16;
    // KV row = 32 uint4; lane m reads uint4 2m, 2m+1 (cols 8m..8m+7)
    const uint4* row = KV4 + (size_t)src * 32 + m * 2;
    uint4 x0 = row[0], x1 = row[1];
    // x: {kpair, vpair, kpair, vpair}
    float d;
    d = bf_lo(x0.x) * q[0];
    d = fmaf(bf_hi(x0.x), q[1], d);
    d = fmaf(bf_lo(x0.z), q[2], d);
    d = fmaf(bf_hi(x0.z), q[3], d);
    d = fmaf(bf_lo(x1.x), q[4], d);
    d = fmaf(bf_hi(x1.x), q[5], d);
    d = fmaf(bf_lo(x1.z), q[6], d);
    d = fmaf(bf_hi(x1.z), q[7], d);
#pragma unroll
    for (int o = 8; o >= 1; o >>= 1) d += __shfl_xor(d, o);
    float pe = __expf(d + qkb[et]);
    pe = valid ? pe : 0.f;
    s += pe;
    const float4* vef = (const float4*)(Vef + et * 128 + m * 8);
    float4 v0 = vef[0], v1 = vef[1];
    a[0] = fmaf(pe, bf_lo(x0.y) + v0.x, a[0]);
    a[1] = fmaf(pe, bf_hi(x0.y) + v0.y, a[1]);
    a[2] = fmaf(pe, bf_lo(x0.w) + v0.z, a[2]);
    a[3] = fmaf(pe, bf_hi(x0.w) + v0.w, a[3]);
    a[4] = fmaf(pe, bf_lo(x1.y) + v1.x, a[4]);
    a[5] = fmaf(pe, bf_hi(x1.y) + v1.y, a[5]);
    a[6] = fmaf(pe, bf_lo(x1.w) + v1.z, a[6]);
    a[7] = fmaf(pe, bf_hi(x1.w) + v1.w, a[7]);
  }
  // cross-group reduce (xor 16, 32)
#pragma unroll
  for (int o = 16; o <= 32; o <<= 1) {
    s += __shfl_xor(s, o);
#pragma unroll
    for (int j = 0; j < 8; ++j) a[j] += __shfl_xor(a[j], o);
  }
  if (g == 0) {
    float inv = (s > 0.f) ? 1.f / s : 0.f;
    u16x8 o;
#pragma unroll
    for (int j = 0; j < 8; ++j) o[j] = f2bf(a[j] * inv);
    *(u16x8*)(hcat_u16 + (size_t)wid * 256 + 128 + m * 8) = o;
  }
}

// ---------------- FFN + residual + LayerNorm (MFMA, weights in LDS, persistent waves) -------
// 256 blocks x 512 threads. W1T (64KB) + W2T (32KB) staged once into LDS with XOR swizzle
// (^((row&7)<<4)) so the stride-512B/256B fragment reads are 2-way-max bank aliased.
// Each wave grid-strides over 16-row tiles (3128 tiles / 2048 waves).
__global__ __launch_bounds__(512) void ffn_mfma_kernel(
    const unsigned short* __restrict__ hcat, const float* __restrict__ hidden,
    const unsigned short* __restrict__ W1T, const unsigned short* __restrict__ W2T,
    const float* __restrict__ b1, const float* __restrict__ b2,
    const float* __restrict__ gamma, const float* __restrict__ beta,
    float* __restrict__ out) {
  __shared__ unsigned short w1s[32768];      // 64KB swizzled [128][256]
  __shared__ unsigned short w2s[16384];      // 32KB swizzled [128][128]
  __shared__ unsigned short mids[8][2176];   // per-wave 16 x 136
  const int tid = threadIdx.x;
  const int w = tid >> 6, l = tid & 63;
  const int lr = l & 15, lg = l >> 4;

  // ---- stage weights (once per block) ----
#pragma unroll
  for (int it = 0; it < 8; ++it) {
    int idx = it * 512 + tid;                // 4096 segs of 8 u16
    int c = idx >> 5, ks8 = idx & 31;
    u16x8 v = *(const u16x8*)(W1T + c * 256 + ks8 * 8);
    int byte = (c * 512 + ks8 * 16) ^ ((c & 7) << 4);
    *(u16x8*)((char*)w1s + byte) = v;
  }
#pragma unroll
  for (int it = 0; it < 4; ++it) {
    int idx = it * 512 + tid;                // 2048 segs
    int c = idx >> 4, ks8 = idx & 15;
    u16x8 v = *(const u16x8*)(W2T + c * 128 + ks8 * 8);
    int byte = (c * 256 + ks8 * 16) ^ ((c & 7) << 4);
    *(u16x8*)((char*)w2s + byte) = v;
  }
  __syncthreads();

  // ---- per-lane constants ----
  float bias1[8], bias2[8], ga[8], be[8];
#pragma unroll
  for (int ct = 0; ct < 8; ++ct) {
    int c = ct * 16 + lr;
    bias1[ct] = b1[c];
    bias2[ct] = b2[c];
    ga[ct] = gamma[c];
    be[ct] = beta[c];
  }
  unsigned short* midw = mids[w];
  const char* w1b = (const char*)w1s;
  const char* w2b = (const char*)w2s;

  for (int t = blockIdx.x * 8 + w; t < NTILES; t += 2048) {
    // A fragments (K=256): 8 x 16B from hcat
    const unsigned short* Ab = hcat + (size_t)(t * 16 + lr) * 256 + lg * 8;
    bf16x8 a[8];
#pragma unroll
    for (int ks = 0; ks < 8; ++ks) a[ks] = *(const bf16x8*)(Ab + ks * 32);

    // GEMM1: K=256 -> 128, B from LDS
    f32x4 acc[8] = {};
#pragma unroll
    for (int ks = 0; ks < 8; ++ks) {
#pragma unroll
      for (int ct = 0; ct < 8; ++ct) {
        int byte = ((ct * 16 + lr) * 512 + (lg * 8 + ks * 32) * 2) ^ ((lr & 7) << 4);
        bf16x8 b = *(const bf16x8*)(w1b + byte);
        acc[ct] = __builtin_amdgcn_mfma_f32_16x16x32_bf16(a[ks], b, acc[ct], 0, 0, 0);
      }
    }

    // residual prefetch (consumed in epilogue; latency hidden under GEMM2)
    float res[8][4];
#pragma unroll
    for (int ct = 0; ct < 8; ++ct)
#pragma unroll
      for (int j = 0; j < 4; ++j) {
        int r = t * 16 + lg * 4 + j;
        res[ct][j] = (r < NN) ? hidden[(size_t)r * 128 + ct * 16 + lr] : 0.f;
      }

    // silu -> per-wave mid buffer
#pragma unroll
    for (int ct = 0; ct < 8; ++ct) {
      float bb = bias1[ct];
#pragma unroll
      for (int j = 0; j < 4; ++j) {
        float x = acc[ct][j] + bb;
        float sl = x / (1.f + __expf(-x));
        midw[(lg * 4 + j) * 136 + ct * 16 + lr] = f2bf(sl);
      }
    }
    asm volatile("s_waitcnt lgkmcnt(0)" ::: "memory");
    __builtin_amdgcn_sched_barrier(0);

    // GEMM2: K=128 -> 128, A from mid, B from LDS
    f32x4 acc2[8] = {};
#pragma unroll
    for (int ks = 0; ks < 4; ++ks) {
      bf16x8 a2 = *(const bf16x8*)(midw + lr * 136 + lg * 8 + ks * 32);
#pragma unroll
      for (int ct = 0; ct < 8; ++ct) {
        int byte = ((ct * 16 + lr) * 256 + (lg * 8 + ks * 32) * 2) ^ ((lr & 7) << 4);
        bf16x8 b = *(const bf16x8*)(w2b + byte);
        acc2[ct] = __builtin_amdgcn_mfma_f32_16x16x32_bf16(a2, b, acc2[ct], 0, 0, 0);
      }
    }

    // epilogue: + b2 + residual, LayerNorm, store
    float x[8][4];
#pragma unroll
    for (int ct = 0; ct < 8; ++ct)
#pragma unroll
      for (int j = 0; j < 4; ++j) x[ct][j] = acc2[ct][j] + bias2[ct] + res[ct][j];
#pragma unroll
    for (int j = 0; j < 4; ++j) {
      float s = 0.f, ss = 0.f;
#pragma unroll
      for (int ct = 0; ct < 8; ++ct) {
        s += x[ct][j];
        ss += x[ct][j] * x[ct][j];
      }
#pragma unroll
      for (int o = 8; o >= 1; o >>= 1) {
        s += __shfl_xor(s, o);
        ss += __shfl_xor(ss, o);
      }
      float mu = s * (1.f / 128.f);
      float inv = rsqrtf(ss * (1.f / 128.f) - mu * mu + EPS);
      int r = t * 16 + lg * 4 + j;
      if (r < NN) {
#pragma unroll
        for (int ct = 0; ct < 8; ++ct) {
          int c = ct * 16 + lr;
          out[(size_t)r * 128 + c] = (x[ct][j] - mu) * inv * ga[ct] + be[ct];
        }
      }
    }
  }
}

extern "C" void kernel_launch(void* const* d_in, const int* in_sizes, int n_in,
                              void* d_out, int out_size, void* d_ws, size_t ws_size,
                              hipStream_t stream) {
  const float* hidden = (const float*)d_in[0];
  const int* edge_index = (const int*)d_in[1];
  const int* edge_type = (const int*)d_in[2];
  const float* edge_emb = (const float*)d_in[3];
  const float* Wq = (const float*)d_in[4];
  const float* bq = (const float*)d_in[5];
  const float* Wk = (const float*)d_in[6];
  const float* bk = (const float*)d_in[7];
  const float* Wv = (const float*)d_in[8];
  const float* bv = (const float*)d_in[9];
  const float* Web = (const float*)d_in[10];
  const float* beb = (const float*)d_in[11];
  const float* W1 = (const float*)d_in[12];
  const float* b1 = (const float*)d_in[13];
  const float* W2 = (const float*)d_in[14];
  const float* b2 = (const float*)d_in[15];
  const float* gamma = (const float*)d_in[16];
  const float* beta = (const float*)d_in[17];
  float* out = (float*)d_out;

  const int* srcp = edge_index;
  const int* tgtp = edge_index + NE;

  size_t off = 0;
  auto alloc = [&](size_t bytes) {
    void* p = (char*)d_ws + off;
    off += (bytes + 255) & ~(size_t)255;
    return p;
  };
  unsigned short* hcat = (unsigned short*)alloc((size_t)NPAD * 256 * 2);  // [h|agg] bf16
  unsigned short* Qb = (unsigned short*)alloc((size_t)NPAD * 128 * 2);    // pre-scaled
  unsigned short* KV = (unsigned short*)alloc((size_t)NPAD * 256 * 2);    // interleaved k/v pairs
  unsigned short* WqkvT = (unsigned short*)alloc(384 * 128 * 2);
  unsigned short* W1T = (unsigned short*)alloc(128 * 256 * 2);
  unsigned short* W2T = (unsigned short*)alloc(128 * 128 * 2);
  float* Kef = (float*)alloc(ET * H * 4);
  float* Vef = (float*)alloc(ET * H * 4);
  float* ebuf = (float*)alloc(ET * 4);
  float* qke = (float*)alloc((size_t)NN * 8 * 4);
  int* deg = (int*)alloc((size_t)NN * 4);
  int* excl = (int*)alloc((size_t)NN * 4);
  int* sums = (int*)alloc(256 * 4);
  int* row_off = (int*)alloc((size_t)(NN + 1) * 4);
  int* cursor = (int*)alloc((size_t)NN * 4);
  int* packed = (int*)alloc((size_t)NE * 4);

  hipMemsetAsync(deg, 0, (size_t)NN * 4, stream);

  const int scan_blocks = (NN + 255) / 256;  // 196

  prep_all_kernel<<<PH_B + PW_B + ET_B + HIST_B, 256, 0, stream>>>(
      hidden, edge_emb, Wq, Wk, Wv, W1, W2, Web, beb, tgtp, hcat, WqkvT, W1T, W2T, Kef, Vef,
      ebuf, deg);
  scan1_kernel<<<scan_blocks, 256, 0, stream>>>(deg, excl, sums);
  scan2_kernel<<<1, 256, 0, stream>>>(sums, scan_blocks);
  scan3_kernel<<<scan_blocks, 256, 0, stream>>>(excl, sums, row_off, cursor);
  scatter_kernel<<<(NE + 255) / 256, 256, 0, stream>>>(srcp, tgtp, edge_type, cursor, packed);
  qkv_mfma_kernel<<<NPAD / 64, 512, 0, stream>>>(hcat, WqkvT, bq, bk, bv, Qb, KV);
  qke_kernel<<<NN / 4, 256, 0, stream>>>(Qb, Kef, ebuf, qke);
  attn_kernel<<<(NN * 64) / 256, 256, 0, stream>>>(Qb, (const uint4*)KV, qke, Vef, row_off,
                                                   packed, hcat);
  ffn_mfma_kernel<<<256, 512, 0, stream>>>(hcat, hidden, W1T, W2T, b1, b2, gamma, beta, out);
}